// Round 4
// baseline (1870.921 us; speedup 1.0000x reference)
//
#include <hip/hip_runtime.h>
#include <math.h>

#define NPB   1024          // nodes per batch/event
#define NB    32            // batches
#define NTOT  (NPB * NB)    // 32768 nodes
#define KNN_K 30
#define FINF  __builtin_inff()

typedef __attribute__((ext_vector_type(8))) short bf16x8;
typedef __attribute__((ext_vector_type(4))) float f32x4;
typedef unsigned short ushort_t;

__device__ inline ushort_t f2bf(float f) {          // RNE f32 -> bf16
  unsigned u = __builtin_bit_cast(unsigned, f);
  u += 0x7FFFu + ((u >> 16) & 1u);
  return (ushort_t)(u >> 16);
}
__device__ inline float bf2f(ushort_t h) {
  return __builtin_bit_cast(float, (unsigned)h << 16);
}

// ---------------------------------------------------------------------------
// node_pre: as = (x@(W1a-W1b)+b1)*s+t ; vs = (x@W1b)*s ; sq = ||x||^2 (f32).
// ---------------------------------------------------------------------------
template<int D>
__global__ __launch_bounds__(256)
void node_pre_kernel(const float* __restrict__ x, int lda,
                     const float* __restrict__ W1, const float* __restrict__ b1,
                     const float* __restrict__ s,  const float* __restrict__ t,
                     ushort_t* __restrict__ as_, ushort_t* __restrict__ vs_,
                     float* __restrict__ sq) {
  const int node = blockIdx.x * 4 + (threadIdx.x >> 6);
  const int c    = threadIdx.x & 63;
  const float* xr = x + (size_t)node * lda;
  float ap = b1[c], vv = 0.f;
  #pragma unroll
  for (int r = 0; r < D; ++r) {
    const float xv = xr[r];                   // wave-uniform row
    const float wa = W1[r * 64 + c];
    const float wb = W1[(D + r) * 64 + c];
    ap += xv * (wa - wb);
    vv += xv * wb;
  }
  const float sc = s[c], tc = t[c];
  as_[(size_t)node * 64 + c] = f2bf(ap * sc + tc);
  vs_[(size_t)node * 64 + c] = f2bf(vv * sc);
  float xv = (c < D) ? xr[c] : 0.f;
  float p = xv * xv;
  #pragma unroll
  for (int o = 32; o > 0; o >>= 1) p += __shfl_down(p, o);
  if (c == 0) sq[node] = p;
}

// ---------------------------------------------------------------------------
// dist: per (batch, 64x64 tile) D2[i][j] = sq_i + sq_j - 2 x_i.x_j. Pure fp32.
// ---------------------------------------------------------------------------
template<int D>
__global__ __launch_bounds__(256)
void dist_kernel(const float* __restrict__ x, int lda,
                 const float* __restrict__ sq,
                 float* __restrict__ d2, int b0) {
  constexpr int PAD = (D == 64) ? 68 : 8;
  __shared__ float Xa[64][PAD];
  __shared__ float Xb[64][PAD];
  __shared__ float sqa[64], sqb[64];
  const int nbase = (b0 + blockIdx.z) * NPB;
  const int i0 = blockIdx.x * 64, j0 = blockIdx.y * 64;
  const int tid = threadIdx.x;

  if constexpr (D == 64) {
    #pragma unroll
    for (int p = 0; p < 4; ++p) {
      const int row = (tid >> 4) + p * 16;
      const int c4 = (tid & 15) * 4;
      const float4 va = *(const float4*)(x + (size_t)(nbase + i0 + row) * lda + c4);
      Xa[row][c4 + 0] = va.x; Xa[row][c4 + 1] = va.y;
      Xa[row][c4 + 2] = va.z; Xa[row][c4 + 3] = va.w;
      const float4 vb = *(const float4*)(x + (size_t)(nbase + j0 + row) * lda + c4);
      Xb[row][c4 + 0] = vb.x; Xb[row][c4 + 1] = vb.y;
      Xb[row][c4 + 2] = vb.z; Xb[row][c4 + 3] = vb.w;
    }
  } else {
    for (int i = tid; i < 64 * D; i += 256) {
      Xa[i / D][i % D] = x[(size_t)(nbase + i0) * lda + i];
      Xb[i / D][i % D] = x[(size_t)(nbase + j0) * lda + i];
    }
  }
  if (tid < 64) sqa[tid] = sq[nbase + i0 + tid];
  else if (tid < 128) sqb[tid - 64] = sq[nbase + j0 + tid - 64];
  __syncthreads();

  const int ti = tid >> 4, tj = tid & 15;
  float acc[4][4];
  #pragma unroll
  for (int u = 0; u < 4; ++u)
    #pragma unroll
    for (int v = 0; v < 4; ++v) acc[u][v] = 0.f;

  if constexpr (D == 64) {
    #pragma unroll
    for (int d4 = 0; d4 < 16; ++d4) {
      float4 a4[4], b4[4];
      #pragma unroll
      for (int u = 0; u < 4; ++u) a4[u] = *(const float4*)(&Xa[ti * 4 + u][d4 * 4]);
      #pragma unroll
      for (int v = 0; v < 4; ++v) b4[v] = *(const float4*)(&Xb[tj * 4 + v][d4 * 4]);
      #pragma unroll
      for (int u = 0; u < 4; ++u)
        #pragma unroll
        for (int v = 0; v < 4; ++v)
          acc[u][v] += a4[u].x * b4[v].x + a4[u].y * b4[v].y
                     + a4[u].z * b4[v].z + a4[u].w * b4[v].w;
    }
  } else {
    #pragma unroll
    for (int d = 0; d < D; ++d) {
      float a[4], b[4];
      #pragma unroll
      for (int u = 0; u < 4; ++u) a[u] = Xa[ti * 4 + u][d];
      #pragma unroll
      for (int v = 0; v < 4; ++v) b[v] = Xb[tj * 4 + v][d];
      #pragma unroll
      for (int u = 0; u < 4; ++u)
        #pragma unroll
        for (int v = 0; v < 4; ++v) acc[u][v] += a[u] * b[v];
    }
  }

  #pragma unroll
  for (int u = 0; u < 4; ++u) {
    const float si = sqa[ti * 4 + u];
    float4 r;
    r.x = si + sqb[tj * 4 + 0] - 2.f * acc[u][0];
    r.y = si + sqb[tj * 4 + 1] - 2.f * acc[u][1];
    r.z = si + sqb[tj * 4 + 2] - 2.f * acc[u][2];
    r.w = si + sqb[tj * 4 + 3] - 2.f * acc[u][3];
    *(float4*)(d2 + ((size_t)blockIdx.z * NPB + i0 + ti * 4 + u) * NPB + j0 + tj * 4) = r;
  }
}

// ---------------------------------------------------------------------------
// select: EXACT top-30 smallest per D2 row via radix-256 rank-select.
// 1 wave/query, 16 values/lane in registers. f32 -> order-preserving u32,
// normalized by wave-min (leading equal bytes become zero and are skipped by
// a uniform mx-check). <=4 histogram passes in wave-private LDS (in-wave DS
// ordering -> no barriers) find exact value T of rank-30 + residual rank r.
// Emit: all u<T plus r ties (j-ordered ranking only on the ~never-taken
// uniform branch). Output order is arbitrary (downstream is max-aggregate).
// ---------------------------------------------------------------------------
__global__ __launch_bounds__(256)
void select_kernel(const float* __restrict__ d2, int b0, int* __restrict__ idx) {
  __shared__ unsigned hist[4][260];
  const int wave = threadIdx.x >> 6, lane = threadIdx.x & 63;
  const int ql = blockIdx.x * 4 + wave;
  const int bl = ql >> 10;
  const int jbase = (b0 + bl) * NPB;
  const int qnode = jbase + (ql & (NPB - 1));
  const float* row = d2 + (size_t)ql * NPB;
  unsigned* h = hist[wave];

  // load + order-preserving map
  unsigned u[16];
  #pragma unroll
  for (int i = 0; i < 16; ++i) {
    const float f = row[lane + (i << 6)];
    const unsigned b = __builtin_bit_cast(unsigned, f);
    u[i] = b ^ ((unsigned)((int)b >> 31) | 0x80000000u);
  }
  // wave min / max
  unsigned mn = u[0], mx = u[0];
  #pragma unroll
  for (int i = 1; i < 16; ++i) { mn = min(mn, u[i]); mx = max(mx, u[i]); }
  #pragma unroll
  for (int o = 1; o < 64; o <<= 1) {
    mn = min(mn, (unsigned)__shfl_xor((int)mn, o));
    mx = max(mx, (unsigned)__shfl_xor((int)mx, o));
  }
  const unsigned mxn = mx - mn;
  #pragma unroll
  for (int i = 0; i < 16; ++i) u[i] -= mn;     // order preserved

  unsigned prefix = 0;
  int rank = KNN_K;                             // 1-based rank within subset
  bool any_hist = false;

  #pragma unroll
  for (int pass = 0; pass < 4; ++pass) {
    const int shift = 24 - pass * 8;
    if (!any_hist && (mxn >> shift) == 0) continue;   // byte uniform(=0): skip
    any_hist = true;
    // zero wave-private histogram (no barrier: DS is in-order per wave)
    *(uint4*)(&h[lane * 4]) = uint4{0u, 0u, 0u, 0u};
    if (lane == 0) h[256] = 0u;
    // histogram elements matching current prefix
    #pragma unroll
    for (int i = 0; i < 16; ++i) {
      const bool inpre = (shift == 24) || ((u[i] >> (shift + 8)) == (prefix >> (shift + 8)));
      const unsigned bin = inpre ? ((u[i] >> shift) & 255u) : 256u;
      atomicAdd(&h[bin], 1u);
    }
    // read back 4 bins/lane + inclusive scan over lanes
    const uint4 c = *(const uint4*)(&h[lane * 4]);
    const unsigned s4 = c.x + c.y + c.z + c.w;
    unsigned sc = s4;
    #pragma unroll
    for (int o = 1; o < 64; o <<= 1) {
      const unsigned v = (unsigned)__shfl_up((int)sc, o);
      if (lane >= o) sc += v;
    }
    const unsigned e0 = sc - s4;
    const unsigned e1 = e0 + c.x, e2 = e1 + c.y, e3 = e2 + c.z, e4 = e3 + c.w;
    // first lane whose inclusive total reaches rank
    const unsigned long long ball = __ballot(e4 >= (unsigned)rank);
    const int cl = __builtin_ctzll(ball);
    const int s0 = (e1 >= (unsigned)rank) ? 0 : (e2 >= (unsigned)rank) ? 1
                 : (e3 >= (unsigned)rank) ? 2 : 3;
    const unsigned bel = (s0 == 0) ? e0 : (s0 == 1) ? e1 : (s0 == 2) ? e2 : e3;
    const int sub      = __shfl(s0, cl);
    const unsigned blw = (unsigned)__shfl((int)bel, cl);
    prefix |= (unsigned)(cl * 4 + sub) << shift;
    rank -= (int)blw;
  }
  const unsigned T = prefix;                    // exact rank-30 value (normalized)

  // emit
  int nlt = 0, neq = 0;
  unsigned ltm = 0, eqm = 0;
  #pragma unroll
  for (int i = 0; i < 16; ++i) {
    const bool lt = u[i] < T, eq = u[i] == T;
    nlt += lt; neq += eq;
    ltm |= (lt ? 1u : 0u) << i;
    eqm |= (eq ? 1u : 0u) << i;
  }
  unsigned pc = (unsigned)nlt | ((unsigned)neq << 16);
  unsigned psc = pc;
  #pragma unroll
  for (int o = 1; o < 64; o <<= 1) {
    const unsigned v = (unsigned)__shfl_up((int)psc, o);
    if (lane >= o) psc += v;
  }
  const unsigned ex = psc - pc;
  const unsigned tot = (unsigned)__shfl((int)psc, 63);
  const int te = (int)(tot >> 16);
  int* out = idx + (size_t)qnode * KNN_K;

  if (te == rank) {                             // common path: take all ties
    int pos = (int)(ex & 0xFFFFu) + (int)(ex >> 16);
    const unsigned selm = ltm | eqm;
    #pragma unroll
    for (int i = 0; i < 16; ++i) {
      if ((selm >> i) & 1u) { out[pos++] = jbase + lane + (i << 6); }
    }
  } else {                                      // rare: rank ties by j-order
    unsigned selm = ltm;
    int base = 0;
    #pragma unroll
    for (int i = 0; i < 16; ++i) {
      const unsigned long long bm = __ballot((eqm >> i) & 1u);
      const int my = base + (int)__popcll(bm & ((1ull << lane) - 1ull));
      if (((eqm >> i) & 1u) && my < rank) selm |= 1u << i;
      base += (int)__popcll(bm);
    }
    int ns = __popc(selm);
    int ssc = ns;
    #pragma unroll
    for (int o = 1; o < 64; o <<= 1) {
      const int v = __shfl_up(ssc, o);
      if (lane >= o) ssc += v;
    }
    int pos = ssc - ns;
    #pragma unroll
    for (int i = 0; i < 16; ++i) {
      if ((selm >> i) & 1u) { out[pos++] = jbase + lane + (i << 6); }
    }
  }
}

// ---------------------------------------------------------------------------
// edge (MFMA): per node, H[32 edges][64] @ W2[64][64] -> col-max over edges.
// ---------------------------------------------------------------------------
__global__ __launch_bounds__(256)
void edge_mfma_kernel(const ushort_t* __restrict__ as_,
                      const ushort_t* __restrict__ vs_,
                      const int* __restrict__ idx,
                      const float* __restrict__ W2, const float* __restrict__ b2,
                      float* __restrict__ xout, ushort_t* __restrict__ xbf,
                      int ldc) {
  const int lane = threadIdx.x & 63;
  const int node = blockIdx.x * 4 + (threadIdx.x >> 6);
  const int g = lane >> 4, r16 = lane & 15;

  bf16x8 bf[2][4];
  #pragma unroll
  for (int ks = 0; ks < 2; ++ks)
    #pragma unroll
    for (int nt = 0; nt < 4; ++nt)
      #pragma unroll
      for (int i = 0; i < 8; ++i)
        bf[ks][nt][i] = (short)f2bf(W2[(ks * 32 + g * 8 + i) * 64 + nt * 16 + r16]);

  float asf[2][8];
  {
    const ushort_t* ar = as_ + (size_t)node * 64;
    #pragma unroll
    for (int ks = 0; ks < 2; ++ks) {
      union { uint4 v; ushort_t s[8]; } u;
      u.v = *(const uint4*)(ar + ks * 32 + g * 8);
      #pragma unroll
      for (int i = 0; i < 8; ++i) asf[ks][i] = bf2f(u.s[i]);
    }
  }

  const int j0 = idx[(size_t)node * KNN_K + r16];
  const int e1 = 16 + r16;
  const int j1 = idx[(size_t)node * KNN_K + (e1 < KNN_K ? e1 : KNN_K - 1)];

  f32x4 acc[2][4];
  #pragma unroll
  for (int mt = 0; mt < 2; ++mt)
    #pragma unroll
    for (int nt = 0; nt < 4; ++nt) acc[mt][nt] = (f32x4)(0.f);

  #pragma unroll
  for (int mt = 0; mt < 2; ++mt) {
    const int j = mt ? j1 : j0;
    const ushort_t* vr = vs_ + (size_t)j * 64;
    #pragma unroll
    for (int ks = 0; ks < 2; ++ks) {
      union { uint4 v; ushort_t s[8]; } u;
      u.v = *(const uint4*)(vr + ks * 32 + g * 8);
      bf16x8 af;
      #pragma unroll
      for (int i = 0; i < 8; ++i) {
        const float hh = fmaxf(asf[ks][i] + bf2f(u.s[i]), 0.f);
        af[i] = (short)f2bf(hh);
      }
      #pragma unroll
      for (int nt = 0; nt < 4; ++nt)
        acc[mt][nt] = __builtin_amdgcn_mfma_f32_16x16x32_bf16(af, bf[ks][nt], acc[mt][nt], 0, 0, 0);
    }
  }

  float cm[4];
  #pragma unroll
  for (int nt = 0; nt < 4; ++nt) {
    float m0 = fmaxf(fmaxf(acc[0][nt][0], acc[0][nt][1]), fmaxf(acc[0][nt][2], acc[0][nt][3]));
    float m1 = fmaxf(fmaxf(acc[1][nt][0], acc[1][nt][1]), fmaxf(acc[1][nt][2], acc[1][nt][3]));
    float m = fmaxf(m0, m1);
    m = fmaxf(m, __shfl_xor(m, 16));
    m = fmaxf(m, __shfl_xor(m, 32));
    cm[nt] = m;
  }
  const float v = (g == 0) ? cm[0] : (g == 1) ? cm[1] : (g == 2) ? cm[2] : cm[3];
  const int c = g * 16 + r16;
  const float o = v + b2[c];
  xout[(size_t)node * ldc + c] = o;
  xbf [(size_t)node * 192 + c] = f2bf(o);
}

// ---------------------------------------------------------------------------
// wcvt: BT[n][k] = bf16(W[k][n])
// ---------------------------------------------------------------------------
__global__ __launch_bounds__(256)
void wcvt_kernel(const float* __restrict__ W, ushort_t* __restrict__ BT,
                 int K, int N) {
  const int i = blockIdx.x * 256 + threadIdx.x;
  if (i >= N * K) return;
  const int n = i / K, k = i % K;
  BT[i] = f2bf(W[(size_t)k * N + n]);
}

// ---------------------------------------------------------------------------
// bf16 MFMA GEMM: C = relu?(A[M,K]bf16 @ B + bias). B passed as BT[N][K] bf16.
// BM=128 BN=128 BK=64, 4 waves (2x2), wave tile 64x64.
// ---------------------------------------------------------------------------
template<bool RELU, typename CT>
__global__ __launch_bounds__(256)
void gemm_bf16_kernel(const ushort_t* __restrict__ A, int lda,
                      const ushort_t* __restrict__ BT, int ldb,
                      const float* __restrict__ bias,
                      CT* __restrict__ C, int ldc, int K) {
  __shared__ ushort_t As[128 * 72];
  __shared__ ushort_t Bs[128 * 72];
  const int tid = threadIdx.x;
  const int lane = tid & 63;
  const int g = lane >> 4, r16 = lane & 15;
  const int wv = tid >> 6, wm = wv >> 1, wn = wv & 1;
  const int bm = blockIdx.x * 128, bn = blockIdx.y * 128;

  f32x4 acc[4][4];
  #pragma unroll
  for (int mt = 0; mt < 4; ++mt)
    #pragma unroll
    for (int nt = 0; nt < 4; ++nt) acc[mt][nt] = (f32x4)(0.f);

  const int srow = tid >> 1, scq = (tid & 1) * 32;
  for (int k0 = 0; k0 < K; k0 += 64) {
    const ushort_t* ap = A + (size_t)(bm + srow) * lda + k0 + scq;
    const ushort_t* bp = BT + (size_t)(bn + srow) * ldb + k0 + scq;
    uint4 av0 = *(const uint4*)(ap);      uint4 av1 = *(const uint4*)(ap + 8);
    uint4 av2 = *(const uint4*)(ap + 16); uint4 av3 = *(const uint4*)(ap + 24);
    uint4 bv0 = *(const uint4*)(bp);      uint4 bv1 = *(const uint4*)(bp + 8);
    uint4 bv2 = *(const uint4*)(bp + 16); uint4 bv3 = *(const uint4*)(bp + 24);
    __syncthreads();
    *(uint4*)(As + srow * 72 + scq +  0) = av0;
    *(uint4*)(As + srow * 72 + scq +  8) = av1;
    *(uint4*)(As + srow * 72 + scq + 16) = av2;
    *(uint4*)(As + srow * 72 + scq + 24) = av3;
    *(uint4*)(Bs + srow * 72 + scq +  0) = bv0;
    *(uint4*)(Bs + srow * 72 + scq +  8) = bv1;
    *(uint4*)(Bs + srow * 72 + scq + 16) = bv2;
    *(uint4*)(Bs + srow * 72 + scq + 24) = bv3;
    __syncthreads();
    #pragma unroll
    for (int ks = 0; ks < 2; ++ks) {
      bf16x8 a[4], b[4];
      #pragma unroll
      for (int mt = 0; mt < 4; ++mt)
        a[mt] = *(const bf16x8*)(As + (wm * 64 + mt * 16 + r16) * 72 + ks * 32 + g * 8);
      #pragma unroll
      for (int nt = 0; nt < 4; ++nt)
        b[nt] = *(const bf16x8*)(Bs + (wn * 64 + nt * 16 + r16) * 72 + ks * 32 + g * 8);
      #pragma unroll
      for (int mt = 0; mt < 4; ++mt)
        #pragma unroll
        for (int nt = 0; nt < 4; ++nt)
          acc[mt][nt] = __builtin_amdgcn_mfma_f32_16x16x32_bf16(a[mt], b[nt], acc[mt][nt], 0, 0, 0);
    }
  }

  #pragma unroll
  for (int nt = 0; nt < 4; ++nt) {
    const int col = bn + wn * 64 + nt * 16 + r16;
    const float bv = bias[col];
    #pragma unroll
    for (int mt = 0; mt < 4; ++mt) {
      #pragma unroll
      for (int r = 0; r < 4; ++r) {
        const int row = bm + wm * 64 + mt * 16 + g * 4 + r;
        float val = acc[mt][nt][r] + bv;
        if (RELU) val = fmaxf(val, 0.f);
        if constexpr (sizeof(CT) == 2) C[(size_t)row * ldc + col] = f2bf(val);
        else                           C[(size_t)row * ldc + col] = val;
      }
    }
  }
}

// ---------------------------------------------------------------------------
// g4: logits = h3[row](bf16) @ W4[128,2] + b4 ; log_softmax. 1 wave/row.
// ---------------------------------------------------------------------------
__global__ __launch_bounds__(64)
void g4_kernel(const ushort_t* __restrict__ h3, const float* __restrict__ W4,
               const float* __restrict__ b4, float* __restrict__ seg) {
  const int row = blockIdx.x;
  const int lane = threadIdx.x;
  const ushort_t* hr = h3 + (size_t)row * 128;
  float p0 = 0.f, p1 = 0.f;
  #pragma unroll
  for (int h = 0; h < 2; ++h) {
    const int r = lane + h * 64;
    const float hv = bf2f(hr[r]);
    p0 += hv * W4[r * 2 + 0];
    p1 += hv * W4[r * 2 + 1];
  }
  #pragma unroll
  for (int o = 32; o > 0; o >>= 1) { p0 += __shfl_down(p0, o); p1 += __shfl_down(p1, o); }
  if (lane == 0) {
    const float l0 = p0 + b4[0], l1 = p1 + b4[1];
    const float mx = fmaxf(l0, l1);
    const float lse = mx + logf(expf(l0 - mx) + expf(l1 - mx));
    seg[(size_t)row * 2 + 0] = l0 - lse;
    seg[(size_t)row * 2 + 1] = l1 - lse;
  }
}

// ---------------------------------------------------------------------------
// wrapper: per event: y = relu(flat @ mW1 + mb1) @ mW2 + mb2 ; log_softmax.
// ---------------------------------------------------------------------------
__global__ __launch_bounds__(256)
void wrapper_kernel(const float* __restrict__ seg, const float* __restrict__ W1,
                    const float* __restrict__ b1, const float* __restrict__ W2,
                    const float* __restrict__ b2, float* __restrict__ out) {
  __shared__ float fl[NPB * 2];
  __shared__ float y1[100];
  __shared__ float l2[2];
  const int b = blockIdx.x, tid = threadIdx.x;
  for (int i = tid; i < NPB * 2; i += 256) fl[i] = seg[(size_t)b * NPB * 2 + i];
  __syncthreads();
  if (tid < 100) {
    float acc = b1[tid];
    for (int r = 0; r < NPB * 2; ++r) acc += fl[r] * W1[(size_t)r * 100 + tid];
    y1[tid] = fmaxf(acc, 0.f);
  }
  __syncthreads();
  if (tid < 2) {
    float acc = b2[tid];
    for (int j = 0; j < 100; ++j) acc += y1[j] * W2[j * 2 + tid];
    l2[tid] = acc;
  }
  __syncthreads();
  if (tid == 0) {
    const float l0 = l2[0], l1 = l2[1];
    const float mx = fmaxf(l0, l1);
    const float lse = mx + logf(expf(l0 - mx) + expf(l1 - mx));
    out[b * 2 + 0] = l0 - lse;
    out[b * 2 + 1] = l1 - lse;
  }
}

// ---------------------------------------------------------------------------
extern "C" void kernel_launch(void* const* d_in, const int* in_sizes, int n_in,
                              void* d_out, int out_size, void* d_ws, size_t ws_size,
                              hipStream_t stream) {
  const float* pos   = (const float*)d_in[0];
  const float* c1_W1 = (const float*)d_in[3];
  const float* c1_b1 = (const float*)d_in[4];
  const float* c1_s  = (const float*)d_in[5];
  const float* c1_t  = (const float*)d_in[6];
  const float* c1_W2 = (const float*)d_in[7];
  const float* c1_b2 = (const float*)d_in[8];
  const float* c2_W1 = (const float*)d_in[9];
  const float* c2_b1 = (const float*)d_in[10];
  const float* c2_s  = (const float*)d_in[11];
  const float* c2_t  = (const float*)d_in[12];
  const float* c2_W2 = (const float*)d_in[13];
  const float* c2_b2 = (const float*)d_in[14];
  const float* c3_W1 = (const float*)d_in[15];
  const float* c3_b1 = (const float*)d_in[16];
  const float* c3_s  = (const float*)d_in[17];
  const float* c3_t  = (const float*)d_in[18];
  const float* c3_W2 = (const float*)d_in[19];
  const float* c3_b2 = (const float*)d_in[20];
  const float* h_W1  = (const float*)d_in[21];
  const float* h_b1  = (const float*)d_in[22];
  const float* h_W2  = (const float*)d_in[23];
  const float* h_b2  = (const float*)d_in[24];
  const float* h_W3  = (const float*)d_in[25];
  const float* h_b3  = (const float*)d_in[26];
  const float* h_W4  = (const float*)d_in[27];
  const float* h_b4  = (const float*)d_in[28];
  const float* m_W1  = (const float*)d_in[29];
  const float* m_b1  = (const float*)d_in[30];
  const float* m_W2  = (const float*)d_in[31];
  const float* m_b2  = (const float*)d_in[32];

  float* ws = (float*)d_ws;
  size_t off = 0;
  auto alloc = [&](size_t n) {
    float* p = ws + off;
    off += (n + 63) & ~(size_t)63;
    return p;
  };
  float*    xfeat = alloc((size_t)NTOT * 192);            // f32 (kNN path)
  ushort_t* xbf   = (ushort_t*)alloc((size_t)NTOT * 96);  // bf16 mirror (gemm A)
  int*      idx   = (int*)alloc((size_t)NTOT * KNN_K);
  ushort_t* asb   = (ushort_t*)alloc((size_t)NTOT * 32);
  ushort_t* vsb   = (ushort_t*)alloc((size_t)NTOT * 32);
  float*    sqb   = alloc(NTOT);
  float*    seg   = alloc((size_t)NTOT * 2);
  ushort_t* BT1   = (ushort_t*)alloc(1024 * 192 / 2);
  ushort_t* BT2   = (ushort_t*)alloc(256 * 1024 / 2);
  ushort_t* BT3   = (ushort_t*)alloc(128 * 256 / 2);

  // Union region: d2 (knn phase) aliases h1/h2/h3 (head phase).
  const size_t totf = ws_size / 4;
  const size_t avail = (totf > off + 1024) ? (totf - off - 1024) : 0;
  int NBC = 32;
  while (NBC > 1 && (size_t)NBC * NPB * NPB > avail) NBC >>= 1;
  int CH = 1;
  while (CH < 256 && (size_t)(NTOT / CH) * 704 > avail) CH <<= 1;
  const int CR = NTOT / CH;
  float* d2buf = ws + off;
  ushort_t* h1 = (ushort_t*)d2buf;
  ushort_t* h2 = h1 + (size_t)CR * 1024;
  ushort_t* h3 = h2 + (size_t)CR * 256;

  // weights -> bf16 transposed (deterministic, every launch)
  wcvt_kernel<<<(192 * 1024 + 255) / 256, 256, 0, stream>>>(h_W1, BT1, 192, 1024);
  wcvt_kernel<<<(1024 * 256 + 255) / 256, 256, 0, stream>>>(h_W2, BT2, 1024, 256);
  wcvt_kernel<<<(256 * 128 + 255) / 256, 256, 0, stream>>>(h_W3, BT3, 256, 128);

  auto run_knn = [&](const float* x, int lda, int D) {
    for (int b0 = 0; b0 < NB; b0 += NBC) {
      if (D == 7) {
        dist_kernel<7><<<dim3(16, 16, NBC), 256, 0, stream>>>(x, lda, sqb, d2buf, b0);
      } else {
        dist_kernel<64><<<dim3(16, 16, NBC), 256, 0, stream>>>(x, lda, sqb, d2buf, b0);
      }
      select_kernel<<<(NBC * NPB) / 4, 256, 0, stream>>>(d2buf, b0, idx);
    }
  };

  // ---- conv1 (pos, D=7) -> cols 0..63
  node_pre_kernel<7><<<NTOT / 4, 256, 0, stream>>>(pos, 7, c1_W1, c1_b1, c1_s, c1_t, asb, vsb, sqb);
  run_knn(pos, 7, 7);
  edge_mfma_kernel<<<NTOT / 4, 256, 0, stream>>>(asb, vsb, idx, c1_W2, c1_b2, xfeat + 0, xbf + 0, 192);
  // ---- conv2 (x1, D=64) -> cols 64..127
  node_pre_kernel<64><<<NTOT / 4, 256, 0, stream>>>(xfeat + 0, 192, c2_W1, c2_b1, c2_s, c2_t, asb, vsb, sqb);
  run_knn(xfeat + 0, 192, 64);
  edge_mfma_kernel<<<NTOT / 4, 256, 0, stream>>>(asb, vsb, idx, c2_W2, c2_b2, xfeat + 64, xbf + 64, 192);
  // ---- conv3 (x2, D=64) -> cols 128..191
  node_pre_kernel<64><<<NTOT / 4, 256, 0, stream>>>(xfeat + 64, 192, c3_W1, c3_b1, c3_s, c3_t, asb, vsb, sqb);
  run_knn(xfeat + 64, 192, 64);
  edge_mfma_kernel<<<NTOT / 4, 256, 0, stream>>>(asb, vsb, idx, c3_W2, c3_b2, xfeat + 128, xbf + 128, 192);

  // ---- head MLP (bf16 MFMA, chunked) + per-node log_softmax
  for (int ch = 0; ch < CH; ++ch) {
    const ushort_t* Ax = xbf + (size_t)ch * CR * 192;
    gemm_bf16_kernel<true, ushort_t><<<dim3(CR / 128, 8), 256, 0, stream>>>(Ax, 192, BT1, 192, h_b1, h1, 1024, 192);
    gemm_bf16_kernel<true, ushort_t><<<dim3(CR / 128, 2), 256, 0, stream>>>(h1, 1024, BT2, 1024, h_b2, h2, 256, 1024);
    gemm_bf16_kernel<true, ushort_t><<<dim3(CR / 128, 1), 256, 0, stream>>>(h2, 256, BT3, 256, h_b3, h3, 128, 256);
    g4_kernel<<<CR, 64, 0, stream>>>(h3, h_W4, h_b4, seg + (size_t)ch * CR * 2);
  }

  // ---- wrapper MLP per event
  wrapper_kernel<<<NB, 256, 0, stream>>>(seg, m_W1, m_b1, m_W2, m_b2, (float*)d_out);
}

// Round 5
// 775.431 us; speedup vs baseline: 2.4127x; 2.4127x over previous
//
#include <hip/hip_runtime.h>
#include <math.h>

#define NPB   1024          // nodes per batch/event
#define NB    32            // batches
#define NTOT  (NPB * NB)    // 32768 nodes
#define KNN_K 30
#define FINF  __builtin_inff()

typedef __attribute__((ext_vector_type(8))) short bf16x8;
typedef __attribute__((ext_vector_type(4))) float f32x4;
typedef unsigned short ushort_t;

__device__ inline ushort_t f2bf(float f) {          // RNE f32 -> bf16
  unsigned u = __builtin_bit_cast(unsigned, f);
  u += 0x7FFFu + ((u >> 16) & 1u);
  return (ushort_t)(u >> 16);
}
__device__ inline float bf2f(ushort_t h) {
  return __builtin_bit_cast(float, (unsigned)h << 16);
}

// ---------------------------------------------------------------------------
// node_pre: as = (x@(W1a-W1b)+b1)*s+t ; vs = (x@W1b)*s ; sq = ||x||^2 (f32).
// ---------------------------------------------------------------------------
template<int D>
__global__ __launch_bounds__(256)
void node_pre_kernel(const float* __restrict__ x, int lda,
                     const float* __restrict__ W1, const float* __restrict__ b1,
                     const float* __restrict__ s,  const float* __restrict__ t,
                     ushort_t* __restrict__ as_, ushort_t* __restrict__ vs_,
                     float* __restrict__ sq) {
  const int node = blockIdx.x * 4 + (threadIdx.x >> 6);
  const int c    = threadIdx.x & 63;
  const float* xr = x + (size_t)node * lda;
  float ap = b1[c], vv = 0.f;
  #pragma unroll
  for (int r = 0; r < D; ++r) {
    const float xv = xr[r];                   // wave-uniform row
    const float wa = W1[r * 64 + c];
    const float wb = W1[(D + r) * 64 + c];
    ap += xv * (wa - wb);
    vv += xv * wb;
  }
  const float sc = s[c], tc = t[c];
  as_[(size_t)node * 64 + c] = f2bf(ap * sc + tc);
  vs_[(size_t)node * 64 + c] = f2bf(vv * sc);
  float xv = (c < D) ? xr[c] : 0.f;
  float p = xv * xv;
  #pragma unroll
  for (int o = 32; o > 0; o >>= 1) p += __shfl_down(p, o);
  if (c == 0) sq[node] = p;
}

// ---------------------------------------------------------------------------
// dist: per (batch, 64x64 tile) D2[i][j] = sq_i + sq_j - 2 x_i.x_j. Pure fp32.
// ---------------------------------------------------------------------------
template<int D>
__global__ __launch_bounds__(256)
void dist_kernel(const float* __restrict__ x, int lda,
                 const float* __restrict__ sq,
                 float* __restrict__ d2, int b0) {
  constexpr int PAD = (D == 64) ? 68 : 8;
  __shared__ float Xa[64][PAD];
  __shared__ float Xb[64][PAD];
  __shared__ float sqa[64], sqb[64];
  const int nbase = (b0 + blockIdx.z) * NPB;
  const int i0 = blockIdx.x * 64, j0 = blockIdx.y * 64;
  const int tid = threadIdx.x;

  if constexpr (D == 64) {
    #pragma unroll
    for (int p = 0; p < 4; ++p) {
      const int row = (tid >> 4) + p * 16;
      const int c4 = (tid & 15) * 4;
      const float4 va = *(const float4*)(x + (size_t)(nbase + i0 + row) * lda + c4);
      Xa[row][c4 + 0] = va.x; Xa[row][c4 + 1] = va.y;
      Xa[row][c4 + 2] = va.z; Xa[row][c4 + 3] = va.w;
      const float4 vb = *(const float4*)(x + (size_t)(nbase + j0 + row) * lda + c4);
      Xb[row][c4 + 0] = vb.x; Xb[row][c4 + 1] = vb.y;
      Xb[row][c4 + 2] = vb.z; Xb[row][c4 + 3] = vb.w;
    }
  } else {
    for (int i = tid; i < 64 * D; i += 256) {
      Xa[i / D][i % D] = x[(size_t)(nbase + i0) * lda + i];
      Xb[i / D][i % D] = x[(size_t)(nbase + j0) * lda + i];
    }
  }
  if (tid < 64) sqa[tid] = sq[nbase + i0 + tid];
  else if (tid < 128) sqb[tid - 64] = sq[nbase + j0 + tid - 64];
  __syncthreads();

  const int ti = tid >> 4, tj = tid & 15;
  float acc[4][4];
  #pragma unroll
  for (int u = 0; u < 4; ++u)
    #pragma unroll
    for (int v = 0; v < 4; ++v) acc[u][v] = 0.f;

  if constexpr (D == 64) {
    #pragma unroll
    for (int d4 = 0; d4 < 16; ++d4) {
      float4 a4[4], b4[4];
      #pragma unroll
      for (int u = 0; u < 4; ++u) a4[u] = *(const float4*)(&Xa[ti * 4 + u][d4 * 4]);
      #pragma unroll
      for (int v = 0; v < 4; ++v) b4[v] = *(const float4*)(&Xb[tj * 4 + v][d4 * 4]);
      #pragma unroll
      for (int u = 0; u < 4; ++u)
        #pragma unroll
        for (int v = 0; v < 4; ++v)
          acc[u][v] += a4[u].x * b4[v].x + a4[u].y * b4[v].y
                     + a4[u].z * b4[v].z + a4[u].w * b4[v].w;
    }
  } else {
    #pragma unroll
    for (int d = 0; d < D; ++d) {
      float a[4], b[4];
      #pragma unroll
      for (int u = 0; u < 4; ++u) a[u] = Xa[ti * 4 + u][d];
      #pragma unroll
      for (int v = 0; v < 4; ++v) b[v] = Xb[tj * 4 + v][d];
      #pragma unroll
      for (int u = 0; u < 4; ++u)
        #pragma unroll
        for (int v = 0; v < 4; ++v) acc[u][v] += a[u] * b[v];
    }
  }

  #pragma unroll
  for (int u = 0; u < 4; ++u) {
    const float si = sqa[ti * 4 + u];
    float4 r;
    r.x = si + sqb[tj * 4 + 0] - 2.f * acc[u][0];
    r.y = si + sqb[tj * 4 + 1] - 2.f * acc[u][1];
    r.z = si + sqb[tj * 4 + 2] - 2.f * acc[u][2];
    r.w = si + sqb[tj * 4 + 3] - 2.f * acc[u][3];
    *(float4*)(d2 + ((size_t)blockIdx.z * NPB + i0 + ti * 4 + u) * NPB + j0 + tj * 4) = r;
  }
}

// ---------------------------------------------------------------------------
// select: top-30 smallest per D2 row. 1 wave/query, 16 vals/lane in registers.
// (1) per-lane min; (2) bitonic sort of 64 lane-minima -> T = 30th smallest
//     (provable upper bound on the true rank-30 value; expected survivors ~40)
// (3) compact survivors (packed (dist&~1023)|j keys) into 128-slot LDS via
//     shfl-scan (plain ds_write, no atomics); (4) bitonic-128 sort (2 regs/
//     lane) -> emit first 30. Wave-uniform fallback (packed extraction) if
//     survivors > 128 (never happens for non-degenerate data).
// ---------------------------------------------------------------------------
__global__ __launch_bounds__(256)
void select_kernel(const float* __restrict__ d2, int b0, int* __restrict__ idx) {
  __shared__ unsigned cbuf[4][128];
  const int wave = threadIdx.x >> 6, lane = threadIdx.x & 63;
  const int ql = blockIdx.x * 4 + wave;
  const int bl = ql >> 10;
  const int jbase = (b0 + bl) * NPB;
  const int qnode = jbase + (ql & (NPB - 1));
  const float* row = d2 + (size_t)ql * NPB;
  int* out = idx + (size_t)qnode * KNN_K;

  // load + order-preserving flip
  unsigned u[16];
  #pragma unroll
  for (int i = 0; i < 16; ++i) {
    const unsigned b = __builtin_bit_cast(unsigned, row[lane + (i << 6)]);
    u[i] = b ^ ((unsigned)((int)b >> 31) | 0x80000000u);
  }

  // per-lane min
  unsigned m = u[0];
  #pragma unroll
  for (int i = 1; i < 16; ++i) m = min(m, u[i]);

  // bitonic sort of 64 lane-minima (ascending by lane)
  #pragma unroll
  for (int k = 2; k <= 64; k <<= 1) {
    #pragma unroll
    for (int jj = k >> 1; jj >= 1; jj >>= 1) {
      const unsigned o = (unsigned)__shfl_xor((int)m, jj);
      const bool up    = ((lane & k) == 0);
      const bool lower = ((lane & jj) == 0);
      m = (lower == up) ? min(m, o) : max(m, o);
    }
  }
  const unsigned T = (unsigned)__shfl((int)m, 29);   // >= true rank-30 value

  // survivor mask + count
  unsigned mask16 = 0; int cnt = 0;
  #pragma unroll
  for (int i = 0; i < 16; ++i) {
    const bool sv = (u[i] <= T);
    mask16 |= (sv ? 1u : 0u) << i;
    cnt += sv;
  }
  // exclusive scan over lanes
  int sc = cnt;
  #pragma unroll
  for (int o = 1; o < 64; o <<= 1) {
    const int v = __shfl_up(sc, o);
    if (lane >= o) sc += v;
  }
  const int base = sc - cnt;
  const int tot  = __shfl(sc, 63);
  unsigned* cb = cbuf[wave];

  if (tot <= 128) {                                  // always, in practice
    int p = base;
    #pragma unroll
    for (int i = 0; i < 16; ++i) {
      if ((mask16 >> i) & 1u)
        cb[p++] = (u[i] & 0xFFFFFC00u) | (unsigned)(lane + (i << 6));
    }
    for (int q = tot + lane; q < 128; q += 64) cb[q] = 0xFFFFFFFFu;
    unsigned r0 = cb[lane];                          // g = lane
    unsigned r1 = cb[lane + 64];                     // g = lane + 64
    // bitonic sort of 128 (2 regs per lane)
    #pragma unroll
    for (int k = 2; k <= 128; k <<= 1) {
      #pragma unroll
      for (int jj = k >> 1; jj >= 1; jj >>= 1) {
        if (jj == 64) {                              // between regs, same lane
          const unsigned lo = min(r0, r1), hi = max(r0, r1);
          r0 = lo; r1 = hi;                          // k=128 only: up for all
        } else {
          const unsigned o0 = (unsigned)__shfl_xor((int)r0, jj);
          const unsigned o1 = (unsigned)__shfl_xor((int)r1, jj);
          const bool lower = ((lane & jj) == 0);
          const bool up0 = ((lane & k) == 0);
          const bool up1 = (((lane + 64) & k) == 0);
          r0 = (lower == up0) ? min(r0, o0) : max(r0, o0);
          r1 = (lower == up1) ? min(r1, o1) : max(r1, o1);
        }
      }
    }
    if (lane < KNN_K) out[lane] = jbase + (int)(r0 & 1023u);
  } else {
    // fallback: packed extraction (exact, slow; not taken for real data)
    unsigned pk[16];
    #pragma unroll
    for (int i = 0; i < 16; ++i)
      pk[i] = (u[i] & 0xFFFFFC00u) | (unsigned)(lane + (i << 6));
    #pragma unroll 1
    for (int k = 0; k < KNN_K; ++k) {
      unsigned best = pk[0];
      #pragma unroll
      for (int i = 1; i < 16; ++i) best = min(best, pk[i]);
      #pragma unroll
      for (int o = 32; o > 0; o >>= 1)
        best = min(best, (unsigned)__shfl_xor((int)best, o));
      if (lane == 0) out[k] = jbase + (int)(best & 1023u);
      #pragma unroll
      for (int i = 0; i < 16; ++i) if (pk[i] == best) pk[i] = 0xFFFFFFFFu;
    }
  }
}

// ---------------------------------------------------------------------------
// edge (MFMA): per node, H[32 edges][64] @ W2[64][64] -> col-max over edges.
// ---------------------------------------------------------------------------
__global__ __launch_bounds__(256)
void edge_mfma_kernel(const ushort_t* __restrict__ as_,
                      const ushort_t* __restrict__ vs_,
                      const int* __restrict__ idx,
                      const float* __restrict__ W2, const float* __restrict__ b2,
                      float* __restrict__ xout, ushort_t* __restrict__ xbf,
                      int ldc) {
  const int lane = threadIdx.x & 63;
  const int node = blockIdx.x * 4 + (threadIdx.x >> 6);
  const int g = lane >> 4, r16 = lane & 15;

  bf16x8 bf[2][4];
  #pragma unroll
  for (int ks = 0; ks < 2; ++ks)
    #pragma unroll
    for (int nt = 0; nt < 4; ++nt)
      #pragma unroll
      for (int i = 0; i < 8; ++i)
        bf[ks][nt][i] = (short)f2bf(W2[(ks * 32 + g * 8 + i) * 64 + nt * 16 + r16]);

  float asf[2][8];
  {
    const ushort_t* ar = as_ + (size_t)node * 64;
    #pragma unroll
    for (int ks = 0; ks < 2; ++ks) {
      union { uint4 v; ushort_t s[8]; } u;
      u.v = *(const uint4*)(ar + ks * 32 + g * 8);
      #pragma unroll
      for (int i = 0; i < 8; ++i) asf[ks][i] = bf2f(u.s[i]);
    }
  }

  const int j0 = idx[(size_t)node * KNN_K + r16];
  const int e1 = 16 + r16;
  const int j1 = idx[(size_t)node * KNN_K + (e1 < KNN_K ? e1 : KNN_K - 1)];

  f32x4 acc[2][4];
  #pragma unroll
  for (int mt = 0; mt < 2; ++mt)
    #pragma unroll
    for (int nt = 0; nt < 4; ++nt) acc[mt][nt] = (f32x4)(0.f);

  #pragma unroll
  for (int mt = 0; mt < 2; ++mt) {
    const int j = mt ? j1 : j0;
    const ushort_t* vr = vs_ + (size_t)j * 64;
    #pragma unroll
    for (int ks = 0; ks < 2; ++ks) {
      union { uint4 v; ushort_t s[8]; } u;
      u.v = *(const uint4*)(vr + ks * 32 + g * 8);
      bf16x8 af;
      #pragma unroll
      for (int i = 0; i < 8; ++i) {
        const float hh = fmaxf(asf[ks][i] + bf2f(u.s[i]), 0.f);
        af[i] = (short)f2bf(hh);
      }
      #pragma unroll
      for (int nt = 0; nt < 4; ++nt)
        acc[mt][nt] = __builtin_amdgcn_mfma_f32_16x16x32_bf16(af, bf[ks][nt], acc[mt][nt], 0, 0, 0);
    }
  }

  float cm[4];
  #pragma unroll
  for (int nt = 0; nt < 4; ++nt) {
    float m0 = fmaxf(fmaxf(acc[0][nt][0], acc[0][nt][1]), fmaxf(acc[0][nt][2], acc[0][nt][3]));
    float m1 = fmaxf(fmaxf(acc[1][nt][0], acc[1][nt][1]), fmaxf(acc[1][nt][2], acc[1][nt][3]));
    float m = fmaxf(m0, m1);
    m = fmaxf(m, __shfl_xor(m, 16));
    m = fmaxf(m, __shfl_xor(m, 32));
    cm[nt] = m;
  }
  const float v = (g == 0) ? cm[0] : (g == 1) ? cm[1] : (g == 2) ? cm[2] : cm[3];
  const int c = g * 16 + r16;
  const float o = v + b2[c];
  xout[(size_t)node * ldc + c] = o;
  xbf [(size_t)node * 192 + c] = f2bf(o);
}

// ---------------------------------------------------------------------------
// wcvt: BT[n][k] = bf16(W[k][n])
// ---------------------------------------------------------------------------
__global__ __launch_bounds__(256)
void wcvt_kernel(const float* __restrict__ W, ushort_t* __restrict__ BT,
                 int K, int N) {
  const int i = blockIdx.x * 256 + threadIdx.x;
  if (i >= N * K) return;
  const int n = i / K, k = i % K;
  BT[i] = f2bf(W[(size_t)k * N + n]);
}

// ---------------------------------------------------------------------------
// bf16 MFMA GEMM: C = relu?(A[M,K]bf16 @ B + bias). B passed as BT[N][K] bf16.
// BM=128 BN=128 BK=64, 4 waves (2x2), wave tile 64x64.
// ---------------------------------------------------------------------------
template<bool RELU, typename CT>
__global__ __launch_bounds__(256)
void gemm_bf16_kernel(const ushort_t* __restrict__ A, int lda,
                      const ushort_t* __restrict__ BT, int ldb,
                      const float* __restrict__ bias,
                      CT* __restrict__ C, int ldc, int K) {
  __shared__ ushort_t As[128 * 72];
  __shared__ ushort_t Bs[128 * 72];
  const int tid = threadIdx.x;
  const int lane = tid & 63;
  const int g = lane >> 4, r16 = lane & 15;
  const int wv = tid >> 6, wm = wv >> 1, wn = wv & 1;
  const int bm = blockIdx.x * 128, bn = blockIdx.y * 128;

  f32x4 acc[4][4];
  #pragma unroll
  for (int mt = 0; mt < 4; ++mt)
    #pragma unroll
    for (int nt = 0; nt < 4; ++nt) acc[mt][nt] = (f32x4)(0.f);

  const int srow = tid >> 1, scq = (tid & 1) * 32;
  for (int k0 = 0; k0 < K; k0 += 64) {
    const ushort_t* ap = A + (size_t)(bm + srow) * lda + k0 + scq;
    const ushort_t* bp = BT + (size_t)(bn + srow) * ldb + k0 + scq;
    uint4 av0 = *(const uint4*)(ap);      uint4 av1 = *(const uint4*)(ap + 8);
    uint4 av2 = *(const uint4*)(ap + 16); uint4 av3 = *(const uint4*)(ap + 24);
    uint4 bv0 = *(const uint4*)(bp);      uint4 bv1 = *(const uint4*)(bp + 8);
    uint4 bv2 = *(const uint4*)(bp + 16); uint4 bv3 = *(const uint4*)(bp + 24);
    __syncthreads();
    *(uint4*)(As + srow * 72 + scq +  0) = av0;
    *(uint4*)(As + srow * 72 + scq +  8) = av1;
    *(uint4*)(As + srow * 72 + scq + 16) = av2;
    *(uint4*)(As + srow * 72 + scq + 24) = av3;
    *(uint4*)(Bs + srow * 72 + scq +  0) = bv0;
    *(uint4*)(Bs + srow * 72 + scq +  8) = bv1;
    *(uint4*)(Bs + srow * 72 + scq + 16) = bv2;
    *(uint4*)(Bs + srow * 72 + scq + 24) = bv3;
    __syncthreads();
    #pragma unroll
    for (int ks = 0; ks < 2; ++ks) {
      bf16x8 a[4], b[4];
      #pragma unroll
      for (int mt = 0; mt < 4; ++mt)
        a[mt] = *(const bf16x8*)(As + (wm * 64 + mt * 16 + r16) * 72 + ks * 32 + g * 8);
      #pragma unroll
      for (int nt = 0; nt < 4; ++nt)
        b[nt] = *(const bf16x8*)(Bs + (wn * 64 + nt * 16 + r16) * 72 + ks * 32 + g * 8);
      #pragma unroll
      for (int mt = 0; mt < 4; ++mt)
        #pragma unroll
        for (int nt = 0; nt < 4; ++nt)
          acc[mt][nt] = __builtin_amdgcn_mfma_f32_16x16x32_bf16(a[mt], b[nt], acc[mt][nt], 0, 0, 0);
    }
  }

  #pragma unroll
  for (int nt = 0; nt < 4; ++nt) {
    const int col = bn + wn * 64 + nt * 16 + r16;
    const float bv = bias[col];
    #pragma unroll
    for (int mt = 0; mt < 4; ++mt) {
      #pragma unroll
      for (int r = 0; r < 4; ++r) {
        const int row = bm + wm * 64 + mt * 16 + g * 4 + r;
        float val = acc[mt][nt][r] + bv;
        if (RELU) val = fmaxf(val, 0.f);
        if constexpr (sizeof(CT) == 2) C[(size_t)row * ldc + col] = f2bf(val);
        else                           C[(size_t)row * ldc + col] = val;
      }
    }
  }
}

// ---------------------------------------------------------------------------
// g4: logits = h3[row](bf16) @ W4[128,2] + b4 ; log_softmax. 1 wave/row.
// ---------------------------------------------------------------------------
__global__ __launch_bounds__(64)
void g4_kernel(const ushort_t* __restrict__ h3, const float* __restrict__ W4,
               const float* __restrict__ b4, float* __restrict__ seg) {
  const int row = blockIdx.x;
  const int lane = threadIdx.x;
  const ushort_t* hr = h3 + (size_t)row * 128;
  float p0 = 0.f, p1 = 0.f;
  #pragma unroll
  for (int h = 0; h < 2; ++h) {
    const int r = lane + h * 64;
    const float hv = bf2f(hr[r]);
    p0 += hv * W4[r * 2 + 0];
    p1 += hv * W4[r * 2 + 1];
  }
  #pragma unroll
  for (int o = 32; o > 0; o >>= 1) { p0 += __shfl_down(p0, o); p1 += __shfl_down(p1, o); }
  if (lane == 0) {
    const float l0 = p0 + b4[0], l1 = p1 + b4[1];
    const float mx = fmaxf(l0, l1);
    const float lse = mx + logf(expf(l0 - mx) + expf(l1 - mx));
    seg[(size_t)row * 2 + 0] = l0 - lse;
    seg[(size_t)row * 2 + 1] = l1 - lse;
  }
}

// ---------------------------------------------------------------------------
// wrapper: per event: y = relu(flat @ mW1 + mb1) @ mW2 + mb2 ; log_softmax.
// ---------------------------------------------------------------------------
__global__ __launch_bounds__(256)
void wrapper_kernel(const float* __restrict__ seg, const float* __restrict__ W1,
                    const float* __restrict__ b1, const float* __restrict__ W2,
                    const float* __restrict__ b2, float* __restrict__ out) {
  __shared__ float fl[NPB * 2];
  __shared__ float y1[100];
  __shared__ float l2[2];
  const int b = blockIdx.x, tid = threadIdx.x;
  for (int i = tid; i < NPB * 2; i += 256) fl[i] = seg[(size_t)b * NPB * 2 + i];
  __syncthreads();
  if (tid < 100) {
    float acc = b1[tid];
    for (int r = 0; r < NPB * 2; ++r) acc += fl[r] * W1[(size_t)r * 100 + tid];
    y1[tid] = fmaxf(acc, 0.f);
  }
  __syncthreads();
  if (tid < 2) {
    float acc = b2[tid];
    for (int j = 0; j < 100; ++j) acc += y1[j] * W2[j * 2 + tid];
    l2[tid] = acc;
  }
  __syncthreads();
  if (tid == 0) {
    const float l0 = l2[0], l1 = l2[1];
    const float mx = fmaxf(l0, l1);
    const float lse = mx + logf(expf(l0 - mx) + expf(l1 - mx));
    out[b * 2 + 0] = l0 - lse;
    out[b * 2 + 1] = l1 - lse;
  }
}

// ---------------------------------------------------------------------------
extern "C" void kernel_launch(void* const* d_in, const int* in_sizes, int n_in,
                              void* d_out, int out_size, void* d_ws, size_t ws_size,
                              hipStream_t stream) {
  const float* pos   = (const float*)d_in[0];
  const float* c1_W1 = (const float*)d_in[3];
  const float* c1_b1 = (const float*)d_in[4];
  const float* c1_s  = (const float*)d_in[5];
  const float* c1_t  = (const float*)d_in[6];
  const float* c1_W2 = (const float*)d_in[7];
  const float* c1_b2 = (const float*)d_in[8];
  const float* c2_W1 = (const float*)d_in[9];
  const float* c2_b1 = (const float*)d_in[10];
  const float* c2_s  = (const float*)d_in[11];
  const float* c2_t  = (const float*)d_in[12];
  const float* c2_W2 = (const float*)d_in[13];
  const float* c2_b2 = (const float*)d_in[14];
  const float* c3_W1 = (const float*)d_in[15];
  const float* c3_b1 = (const float*)d_in[16];
  const float* c3_s  = (const float*)d_in[17];
  const float* c3_t  = (const float*)d_in[18];
  const float* c3_W2 = (const float*)d_in[19];
  const float* c3_b2 = (const float*)d_in[20];
  const float* h_W1  = (const float*)d_in[21];
  const float* h_b1  = (const float*)d_in[22];
  const float* h_W2  = (const float*)d_in[23];
  const float* h_b2  = (const float*)d_in[24];
  const float* h_W3  = (const float*)d_in[25];
  const float* h_b3  = (const float*)d_in[26];
  const float* h_W4  = (const float*)d_in[27];
  const float* h_b4  = (const float*)d_in[28];
  const float* m_W1  = (const float*)d_in[29];
  const float* m_b1  = (const float*)d_in[30];
  const float* m_W2  = (const float*)d_in[31];
  const float* m_b2  = (const float*)d_in[32];

  float* ws = (float*)d_ws;
  size_t off = 0;
  auto alloc = [&](size_t n) {
    float* p = ws + off;
    off += (n + 63) & ~(size_t)63;
    return p;
  };
  float*    xfeat = alloc((size_t)NTOT * 192);            // f32 (kNN path)
  ushort_t* xbf   = (ushort_t*)alloc((size_t)NTOT * 96);  // bf16 mirror (gemm A)
  int*      idx   = (int*)alloc((size_t)NTOT * KNN_K);
  ushort_t* asb   = (ushort_t*)alloc((size_t)NTOT * 32);
  ushort_t* vsb   = (ushort_t*)alloc((size_t)NTOT * 32);
  float*    sqb   = alloc(NTOT);
  float*    seg   = alloc((size_t)NTOT * 2);
  ushort_t* BT1   = (ushort_t*)alloc(1024 * 192 / 2);
  ushort_t* BT2   = (ushort_t*)alloc(256 * 1024 / 2);
  ushort_t* BT3   = (ushort_t*)alloc(128 * 256 / 2);

  // Union region: d2 (knn phase) aliases h1/h2/h3 (head phase).
  const size_t totf = ws_size / 4;
  const size_t avail = (totf > off + 1024) ? (totf - off - 1024) : 0;
  int NBC = 32;
  while (NBC > 1 && (size_t)NBC * NPB * NPB > avail) NBC >>= 1;
  int CH = 1;
  while (CH < 256 && (size_t)(NTOT / CH) * 704 > avail) CH <<= 1;
  const int CR = NTOT / CH;
  float* d2buf = ws + off;
  ushort_t* h1 = (ushort_t*)d2buf;
  ushort_t* h2 = h1 + (size_t)CR * 1024;
  ushort_t* h3 = h2 + (size_t)CR * 256;

  // weights -> bf16 transposed (deterministic, every launch)
  wcvt_kernel<<<(192 * 1024 + 255) / 256, 256, 0, stream>>>(h_W1, BT1, 192, 1024);
  wcvt_kernel<<<(1024 * 256 + 255) / 256, 256, 0, stream>>>(h_W2, BT2, 1024, 256);
  wcvt_kernel<<<(256 * 128 + 255) / 256, 256, 0, stream>>>(h_W3, BT3, 256, 128);

  auto run_knn = [&](const float* x, int lda, int D) {
    for (int b0 = 0; b0 < NB; b0 += NBC) {
      if (D == 7) {
        dist_kernel<7><<<dim3(16, 16, NBC), 256, 0, stream>>>(x, lda, sqb, d2buf, b0);
      } else {
        dist_kernel<64><<<dim3(16, 16, NBC), 256, 0, stream>>>(x, lda, sqb, d2buf, b0);
      }
      select_kernel<<<(NBC * NPB) / 4, 256, 0, stream>>>(d2buf, b0, idx);
    }
  };

  // ---- conv1 (pos, D=7) -> cols 0..63
  node_pre_kernel<7><<<NTOT / 4, 256, 0, stream>>>(pos, 7, c1_W1, c1_b1, c1_s, c1_t, asb, vsb, sqb);
  run_knn(pos, 7, 7);
  edge_mfma_kernel<<<NTOT / 4, 256, 0, stream>>>(asb, vsb, idx, c1_W2, c1_b2, xfeat + 0, xbf + 0, 192);
  // ---- conv2 (x1, D=64) -> cols 64..127
  node_pre_kernel<64><<<NTOT / 4, 256, 0, stream>>>(xfeat + 0, 192, c2_W1, c2_b1, c2_s, c2_t, asb, vsb, sqb);
  run_knn(xfeat + 0, 192, 64);
  edge_mfma_kernel<<<NTOT / 4, 256, 0, stream>>>(asb, vsb, idx, c2_W2, c2_b2, xfeat + 64, xbf + 64, 192);
  // ---- conv3 (x2, D=64) -> cols 128..191
  node_pre_kernel<64><<<NTOT / 4, 256, 0, stream>>>(xfeat + 64, 192, c3_W1, c3_b1, c3_s, c3_t, asb, vsb, sqb);
  run_knn(xfeat + 64, 192, 64);
  edge_mfma_kernel<<<NTOT / 4, 256, 0, stream>>>(asb, vsb, idx, c3_W2, c3_b2, xfeat + 128, xbf + 128, 192);

  // ---- head MLP (bf16 MFMA, chunked) + per-node log_softmax
  for (int ch = 0; ch < CH; ++ch) {
    const ushort_t* Ax = xbf + (size_t)ch * CR * 192;
    gemm_bf16_kernel<true, ushort_t><<<dim3(CR / 128, 8), 256, 0, stream>>>(Ax, 192, BT1, 192, h_b1, h1, 1024, 192);
    gemm_bf16_kernel<true, ushort_t><<<dim3(CR / 128, 2), 256, 0, stream>>>(h1, 1024, BT2, 1024, h_b2, h2, 256, 1024);
    gemm_bf16_kernel<true, ushort_t><<<dim3(CR / 128, 1), 256, 0, stream>>>(h2, 256, BT3, 256, h_b3, h3, 128, 256);
    g4_kernel<<<CR, 64, 0, stream>>>(h3, h_W4, h_b4, seg + (size_t)ch * CR * 2);
  }

  // ---- wrapper MLP per event
  wrapper_kernel<<<NB, 256, 0, stream>>>(seg, m_W1, m_b1, m_W2, m_b2, (float*)d_out);
}